// Round 19
// baseline (623.453 us; speedup 1.0000x reference)
//
#include <hip/hip_runtime.h>
#include <hip/hip_bf16.h>
#include <cmath>

typedef __bf16 bf16x8 __attribute__((ext_vector_type(8)));
typedef float f32x4 __attribute__((ext_vector_type(4)));
typedef float f32x16 __attribute__((ext_vector_type(16)));
typedef unsigned short u16;
typedef unsigned int u32;

#define DEV __device__ __forceinline__

static constexpr int BB = 2;
static constexpr int T = 2048;
static constexpr int DM = 2048;
static constexpr int NH = 16;
static constexpr int HD = 128;
static constexpr int FF = 8192;
static constexpr int M = BB * T;      // 4096
static constexpr int NQKV = 3 * DM;   // 6144

DEV u16 f2b(float f) {
  u32 u = __builtin_bit_cast(u32, f);
  u = (u + 0x7FFFu + ((u >> 16) & 1u)) >> 16;
  return (u16)u;
}
DEV float b2f(u16 h) {
  u32 u = ((u32)h) << 16;
  return __builtin_bit_cast(float, u);
}

// async global->LDS, 16B per lane; LDS dest = wave-uniform base + lane*16
DEV void gload16(const u16* g, const u16* l) {
  __builtin_amdgcn_global_load_lds(
      (const __attribute__((address_space(1))) void*)(uintptr_t)g,
      (__attribute__((address_space(3))) void*)(unsigned)(uintptr_t)l,
      16, 0, 0);
}

// ---------------- conversions ----------------

__global__ void cvt_f32_to_bf16(const float* __restrict__ in, u16* __restrict__ out, int n4) {
  int i = blockIdx.x * blockDim.x + threadIdx.x;
  if (i >= n4) return;
  float4 v = reinterpret_cast<const float4*>(in)[i];
  ushort4 o;
  o.x = f2b(v.x); o.y = f2b(v.y); o.z = f2b(v.z); o.w = f2b(v.w);
  reinterpret_cast<ushort4*>(out)[i] = o;
}

// W [K][N] f32 -> Wt [N][K] bf16; 32x32 tile, float4 read + ushort4 write
__global__ void transpose_cvt(const float* __restrict__ W, u16* __restrict__ Wt, int K, int N) {
  __shared__ float tile[32][33];
  int nb = blockIdx.x * 32, kb = blockIdx.y * 32;
  int r = threadIdx.x >> 3;         // 0..31
  int c4 = (threadIdx.x & 7) * 4;   // 0..28
  float4 v = *reinterpret_cast<const float4*>(&W[(size_t)(kb + r) * N + nb + c4]);
  tile[r][c4] = v.x; tile[r][c4 + 1] = v.y; tile[r][c4 + 2] = v.z; tile[r][c4 + 3] = v.w;
  __syncthreads();
  ushort4 o;
  o.x = f2b(tile[c4][r]);     o.y = f2b(tile[c4 + 1][r]);
  o.z = f2b(tile[c4 + 2][r]); o.w = f2b(tile[c4 + 3][r]);
  *reinterpret_cast<ushort4*>(&Wt[(size_t)(nb + r) * K + kb + c4]) = o;
}

// FF2 reduce: out = p0 + p1 + bias + x + attn_proj (split-K join + residuals)
__global__ void ff2_reduce(const float* __restrict__ p0, const float* __restrict__ p1,
                           const float* __restrict__ bias, const float* __restrict__ x,
                           const u16* __restrict__ ap, float* __restrict__ out) {
  int i = blockIdx.x * blockDim.x + threadIdx.x;  // float4 index, exact grid
  float4 a = reinterpret_cast<const float4*>(p0)[i];
  float4 b = reinterpret_cast<const float4*>(p1)[i];
  float4 xx = reinterpret_cast<const float4*>(x)[i];
  float4 bi = reinterpret_cast<const float4*>(bias)[i & (DM / 4 - 1)];
  ushort4 a4 = reinterpret_cast<const ushort4*>(ap)[i];
  float4 o;
  o.x = a.x + b.x + bi.x + xx.x + b2f(a4.x);
  o.y = a.y + b.y + bi.y + xx.y + b2f(a4.y);
  o.z = a.z + b.z + bi.z + xx.z + b2f(a4.z);
  o.w = a.w + b.w + bi.w + xx.w + b2f(a4.w);
  reinterpret_cast<float4*>(out)[i] = o;
}

// ---------------- 8-phase GEMM (256x256, BK=64), balanced reads ----------------
// (frozen schedule — round 13) 8 waves 2M x 4N, wave tile 128x64. 4 phases
// per K-tile, reads spread 4/8/0/12, counted vmcnt(8) publishes tile kt+1 one
// phase early; chunk-XOR swizzle; XCD-bijective block swizzle; setprio.
// EPI 0: q/k fragment scatter; EPI 2: bias+GELU; EPI 5: f32 split-K partial.
template <int EPI>
__global__ __launch_bounds__(512, 2) void gemm8(
    const u16* __restrict__ A, const u16* __restrict__ Bt, int Ndim,
    int Kstride, int Klen, int gx, int tpp,
    u16* __restrict__ out_bf, float* __restrict__ p0, float* __restrict__ p1,
    const float* __restrict__ bias) {
  __shared__ __align__(16) u16 lds[2 * 32768];  // 128 KB
  const int t = threadIdx.x;
  const int nwg = gridDim.x, cpx = nwg >> 3;
  const int wg = (blockIdx.x & 7) * cpx + (blockIdx.x >> 3);
  const int part = wg / tpp, tid = wg % tpp;
  const int m0 = (tid / gx) * 256, n0 = (tid % gx) * 256;
  const int wave = t >> 6, lane = t & 63;
  const int wm = wave >> 2, wn = wave & 3;
  const int lr = lane & 15, lk = lane >> 4;

  const int srow = t >> 3;
  const int sc8 = ((t & 7) ^ (srow & 7)) * 8;
  const u16* gA = &A[(size_t)(m0 + srow) * Kstride + (size_t)part * Klen + sc8];
  const u16* gB = &Bt[(size_t)(n0 + srow) * Kstride + (size_t)part * Klen + sc8];
  const int wls = wave * 512;

  u16* buf0 = lds;
  u16* buf1 = lds + 32768;

#define STAGE_A(buf, h, kt)                                                      \
  {                                                                              \
    gload16(gA + (size_t)((h) * 128) * Kstride + (kt) * 64,                      \
            (buf) + (h) * 8192 + wls);                                           \
    gload16(gA + (size_t)((h) * 128 + 64) * Kstride + (kt) * 64,                 \
            (buf) + (h) * 8192 + 4096 + wls);                                    \
  }
#define STAGE_B(buf, h, kt)                                                      \
  {                                                                              \
    gload16(gB + (size_t)((h) * 128) * Kstride + (kt) * 64,                      \
            (buf) + 16384 + (h) * 8192 + wls);                                   \
    gload16(gB + (size_t)((h) * 128 + 64) * Kstride + (kt) * 64,                 \
            (buf) + 16384 + (h) * 8192 + 4096 + wls);                            \
  }
#define BARR                            \
  __builtin_amdgcn_sched_barrier(0);    \
  __builtin_amdgcn_s_barrier();         \
  __builtin_amdgcn_sched_barrier(0);

  const int NT = Klen >> 6;

  // prologue: all of tile 0 (8 loads), all of tile 1 (8 loads); wait tile 0
  STAGE_B(buf0, 0, 0); STAGE_B(buf0, 1, 0);
  STAGE_A(buf0, 0, 0); STAGE_A(buf0, 1, 0);
  STAGE_B(buf1, 0, 1); STAGE_B(buf1, 1, 1);
  STAGE_A(buf1, 0, 1); STAGE_A(buf1, 1, 1);
  __builtin_amdgcn_sched_barrier(0);
  asm volatile("s_waitcnt vmcnt(8)" ::: "memory");
  __builtin_amdgcn_s_barrier();
  __builtin_amdgcn_sched_barrier(0);

  f32x4 acc[8][4] = {};
  const int aBase = (wm * 128 + lr) * 64;
  const int bBase = 16384 + (wn * 64 + lr) * 64;
  const int c0 = (lk ^ (lr & 7)) * 8;
  const int c1 = ((4 + lk) ^ (lr & 7)) * 8;

  u16* cur = buf0;
  u16* alt = buf1;
  bf16x8 a03[4][2], a47[4][2], b01[2][2], b23[2][2];

  // pre-loop: A03 + B01 of K-tile 0
#pragma unroll
  for (int i = 0; i < 4; ++i) {
    a03[i][0] = *(const bf16x8*)&cur[aBase + i * 1024 + c0];
    a03[i][1] = *(const bf16x8*)&cur[aBase + i * 1024 + c1];
  }
#pragma unroll
  for (int j = 0; j < 2; ++j) {
    b01[j][0] = *(const bf16x8*)&cur[bBase + j * 1024 + c0];
    b01[j][1] = *(const bf16x8*)&cur[bBase + j * 1024 + c1];
  }

  for (int kt = 0; kt < NT; ++kt) {
    // p0: read b23 || MFMA q00(a03,b01)
#pragma unroll
    for (int j = 0; j < 2; ++j) {
      b23[j][0] = *(const bf16x8*)&cur[bBase + (2 + j) * 1024 + c0];
      b23[j][1] = *(const bf16x8*)&cur[bBase + (2 + j) * 1024 + c1];
    }
    __builtin_amdgcn_s_setprio(1);
#pragma unroll
    for (int i = 0; i < 4; ++i)
#pragma unroll
      for (int j = 0; j < 2; ++j)
#pragma unroll
        for (int kk = 0; kk < 2; ++kk)
          acc[i][j] = __builtin_amdgcn_mfma_f32_16x16x32_bf16(a03[i][kk], b01[j][kk], acc[i][j], 0, 0, 0);
    __builtin_amdgcn_s_setprio(0);
    BARR;
    // p1: stage cur.Bh0+Bh1(kt+2); read a47 || MFMA q01(a03,b23)
    if (kt + 2 < NT) { STAGE_B(cur, 0, kt + 2); STAGE_B(cur, 1, kt + 2); }
#pragma unroll
    for (int i = 0; i < 4; ++i) {
      a47[i][0] = *(const bf16x8*)&cur[aBase + (4 + i) * 1024 + c0];
      a47[i][1] = *(const bf16x8*)&cur[aBase + (4 + i) * 1024 + c1];
    }
    __builtin_amdgcn_s_setprio(1);
#pragma unroll
    for (int i = 0; i < 4; ++i)
#pragma unroll
      for (int j = 0; j < 2; ++j)
#pragma unroll
        for (int kk = 0; kk < 2; ++kk)
          acc[i][2 + j] = __builtin_amdgcn_mfma_f32_16x16x32_bf16(a03[i][kk], b23[j][kk], acc[i][2 + j], 0, 0, 0);
    __builtin_amdgcn_s_setprio(0);
    BARR;
    // p2: stage cur.Ah0+Ah1(kt+2); MFMA q10(a47,b01); publish tile kt+1
    if (kt + 2 < NT) { STAGE_A(cur, 0, kt + 2); STAGE_A(cur, 1, kt + 2); }
    __builtin_amdgcn_s_setprio(1);
#pragma unroll
    for (int i = 0; i < 4; ++i)
#pragma unroll
      for (int j = 0; j < 2; ++j)
#pragma unroll
        for (int kk = 0; kk < 2; ++kk)
          acc[4 + i][j] = __builtin_amdgcn_mfma_f32_16x16x32_bf16(a47[i][kk], b01[j][kk], acc[4 + i][j], 0, 0, 0);
    __builtin_amdgcn_s_setprio(0);
    __builtin_amdgcn_sched_barrier(0);
    if (kt + 2 < NT)      asm volatile("s_waitcnt vmcnt(8)" ::: "memory");
    else if (kt + 1 < NT) asm volatile("s_waitcnt vmcnt(0)" ::: "memory");
    __builtin_amdgcn_s_barrier();
    __builtin_amdgcn_sched_barrier(0);
    // p3: read NEXT a03/b01 from alt || MFMA q11(a47,b23)
    if (kt + 1 < NT) {
#pragma unroll
      for (int i = 0; i < 4; ++i) {
        a03[i][0] = *(const bf16x8*)&alt[aBase + i * 1024 + c0];
        a03[i][1] = *(const bf16x8*)&alt[aBase + i * 1024 + c1];
      }
#pragma unroll
      for (int j = 0; j < 2; ++j) {
        b01[j][0] = *(const bf16x8*)&alt[bBase + j * 1024 + c0];
        b01[j][1] = *(const bf16x8*)&alt[bBase + j * 1024 + c1];
      }
    }
    __builtin_amdgcn_s_setprio(1);
#pragma unroll
    for (int i = 0; i < 4; ++i)
#pragma unroll
      for (int j = 0; j < 2; ++j)
#pragma unroll
        for (int kk = 0; kk < 2; ++kk)
          acc[4 + i][2 + j] = __builtin_amdgcn_mfma_f32_16x16x32_bf16(a47[i][kk], b23[j][kk], acc[4 + i][2 + j], 0, 0, 0);
    __builtin_amdgcn_s_setprio(0);
    BARR;
    u16* tmp = cur; cur = alt; alt = tmp;
  }
#undef STAGE_A
#undef STAGE_B
#undef BARR

  float* pout = (part == 0) ? p0 : p1;
#pragma unroll
  for (int i = 0; i < 8; ++i) {
#pragma unroll
    for (int j = 0; j < 4; ++j) {
#pragma unroll
      for (int r = 0; r < 4; ++r) {
        int gr = m0 + wm * 128 + i * 16 + (lane >> 4) * 4 + r;
        int gc = n0 + wn * 64 + j * 16 + (lane & 15);
        float v = acc[i][j][r];
        if constexpr (EPI == 0) {
          // q/k scatter in fragment layout:
          // frag[bh][tb=tt>>5][s=d>>4][lane=(tt&31)+32*((d>>3)&1)][j=d&7]
          int part_ = gc >> 11, cc = gc & 2047;
          int head = cc >> 7, d = cc & 127;
          int b = gr >> 11, tt = gr & 2047;
          int bh = b * NH + head;
          size_t addr = (((size_t)(bh * 64 + (tt >> 5)) * 8 + (d >> 4)) * 512)
                        + ((tt & 31) + ((d >> 3) & 1) * 32) * 8 + (d & 7);
          out_bf[(size_t)part_ * M * DM + addr] = f2b(v);
        } else if constexpr (EPI == 2) {  // bias + tanh-GELU
          v += bias[gc];
          float u = v * (v * v * 0.044715f + 1.0f) * 0.7978845608028654f;
          float e = exp2f(u * 2.885390081777927f);
          float th = 1.0f - 2.0f / (e + 1.0f);
          v = 0.5f * v * (1.0f + th);
          out_bf[(size_t)gr * Ndim + gc] = f2b(v);
        } else {  // EPI 5: f32 partial
          pout[(size_t)gr * Ndim + gc] = v;
        }
      }
    }
  }
}

// ---------------- GEMM (256x128, 8 waves 64x64) ----------------
// (verified) 3-buffer pipeline, counted vmcnt(3), raw s_barrier, chunk
// swizzle, XCD-bijective block swizzle.
// EPI 1: plain bf16; EPI 4: V-FRAGMENT scatter.
template <int EPI>
__global__ __launch_bounds__(512, 4) void gemm_bf16(
    const u16* __restrict__ A, const u16* __restrict__ Bt, int Ndim, int K, int gx,
    u16* __restrict__ out_bf) {
  __shared__ __align__(16) u16 lds[3 * (256 + 128) * 32];  // 72 KB
  const int t = threadIdx.x;
  const int nwg = gridDim.x, cpx = nwg >> 3;
  const int wg = (blockIdx.x & 7) * cpx + (blockIdx.x >> 3);
  const int m0 = (wg / gx) * 256, n0 = (wg % gx) * 128;
  const int wave = t >> 6, lane = t & 63;
  const int wm = wave >> 1, wn = wave & 1;
  const int lr = lane & 15, lk = lane >> 4;

  u16* cA = lds;                   u16* cB = lds + 8192;
  u16* nA = lds + 12288;           u16* nB = lds + 12288 + 8192;
  u16* sA = lds + 2 * 12288;       u16* sB = lds + 2 * 12288 + 8192;

  const int sk = ((lane & 3) ^ ((lane >> 3) & 3)) * 8;
  const u16* gA0 = &A[(size_t)(m0 + wave * 16 + (lane >> 2)) * K + sk];
  const u16* gA1 = gA0 + (size_t)128 * K;
  const u16* gB0 = &Bt[(size_t)(n0 + wave * 16 + (lane >> 2)) * K + sk];

  const int wbase = wave * 512;

  auto stage = [&](u16* dA, u16* dB) {
    gload16(gA0, dA + wbase);
    gload16(gA1, dA + 4096 + wbase);
    gload16(gB0, dB + wbase);
    gA0 += 32; gA1 += 32; gB0 += 32;
  };

  const int NT = K >> 5;

  stage(cA, cB);
  stage(nA, nB);
  __builtin_amdgcn_sched_barrier(0);
  asm volatile("s_waitcnt vmcnt(3)" ::: "memory");
  __builtin_amdgcn_s_barrier();
  __builtin_amdgcn_sched_barrier(0);

  f32x4 acc[4][4] = {};
  const int rcol = (lk ^ ((lr >> 1) & 3)) * 8;

  for (int kt = 0; kt < NT; ++kt) {
    if (kt + 2 < NT) stage(sA, sB);
    bf16x8 af[4], bfr[4];
#pragma unroll
    for (int i = 0; i < 4; ++i) {
      af[i]  = *reinterpret_cast<const bf16x8*>(&cA[(wm * 64 + i * 16 + lr) * 32 + rcol]);
      bfr[i] = *reinterpret_cast<const bf16x8*>(&cB[(wn * 64 + i * 16 + lr) * 32 + rcol]);
    }
#pragma unroll
    for (int i = 0; i < 4; ++i)
#pragma unroll
      for (int j = 0; j < 4; ++j)
        acc[i][j] = __builtin_amdgcn_mfma_f32_16x16x32_bf16(af[i], bfr[j], acc[i][j], 0, 0, 0);
    if (kt + 1 < NT) {
      __builtin_amdgcn_sched_barrier(0);
      if (kt + 2 < NT) asm volatile("s_waitcnt vmcnt(3)" ::: "memory");
      else             asm volatile("s_waitcnt vmcnt(0)" ::: "memory");
      __builtin_amdgcn_s_barrier();
      __builtin_amdgcn_sched_barrier(0);
      u16* tA = cA; u16* tB = cB;
      cA = nA; cB = nB; nA = sA; nB = sB; sA = tA; sB = tB;
    }
  }

#pragma unroll
  for (int i = 0; i < 4; ++i) {
#pragma unroll
    for (int j = 0; j < 4; ++j) {
#pragma unroll
      for (int r = 0; r < 4; ++r) {
        int gr = m0 + wm * 64 + i * 16 + (lane >> 4) * 4 + r;
        int gc = n0 + wn * 64 + j * 16 + (lane & 15);
        float v = acc[i][j][r];
        if constexpr (EPI == 1) {
          out_bf[(size_t)gr * Ndim + gc] = f2b(v);
        } else {
          // EPI 4: V fragment layout. This GEMM computes V^T: gr = feature
          // (hh*128+d), gc = token (b*2048+tt).
          // vfrag[bh][kv16=tt>>4][dblk=d>>5][lane=(d&31)+32*((tt>>3)&1)][j=tt&7]
          int hh = gr >> 7, d = gr & 127;
          int b = gc >> 11, tt = gc & 2047;
          int bh = b * NH + hh;
          size_t addr = (((size_t)(bh * 128 + (tt >> 4)) * 4 + (d >> 5)) * 512)
                        + ((d & 31) + ((tt >> 3) & 1) * 32) * 8 + (tt & 7);
          out_bf[addr] = f2b(v);
        }
      }
    }
  }
}

// ---------------- attention (fragment-layout, 32x32 MFMA, no LDS) ----------
// (verified body) grid (T/128, B*NH), 4 waves x 32 q-rows. K AND V register
// double-buffering: tile kt+1's K and V loads issue right after tile kt's
// S-MFMAs (kfr dead there); softmax+pack covers the latency; PV runs fully
// out of registers. launch_bounds(256,2) caps VGPR at 256 (2 waves/SIMD).
__global__ __launch_bounds__(256, 2) void attn_frag(
    const u16* __restrict__ qf_, const u16* __restrict__ kf_,
    const u16* __restrict__ vf_, u16* __restrict__ outg) {
  const int l = threadIdx.x & 63;
  const int wq = threadIdx.x >> 6;
  const int bh = blockIdx.y;
  const int qi = gridDim.x - 1 - blockIdx.x;  // longest-first
  const int qb = qi * 4 + wq;                 // 32-row band index, 0..63
  const int h = l >> 5, ln = l & 31;
  const int qrow = qb * 32 + ln;              // this lane's q-row

  // Q fragments (8 d-slices)
  const u16* qbase = qf_ + ((size_t)(bh * 64 + qb) * 8) * 512 + l * 8;
  bf16x8 qf[8];
#pragma unroll
  for (int s = 0; s < 8; ++s)
    qf[s] = *reinterpret_cast<const bf16x8*>(qbase + s * 512);

  f32x16 acc0 = {}, acc1 = {}, acc2 = {}, acc3 = {};
  float mrow = -INFINITY, lrow = 0.f;
  const float scaleL = 0.08838834764831845f * 1.4426950408889634f;
  const int ntiles = qb + 1;

  // prologue: K and V fragments of tile 0
  bf16x8 kfr[8], kfn[8], vfr[8], vfn[8];
  {
    const u16* kb0 = kf_ + ((size_t)(bh * 64 + 0) * 8) * 512 + l * 8;
    const u16* vb0 = vf_ + ((size_t)(bh * 128 + 0) * 4) * 512 + l * 8;
#pragma unroll
    for (int s = 0; s < 8; ++s) {
      kfr[s] = *reinterpret_cast<const bf16x8*>(kb0 + s * 512);
      vfr[s] = *reinterpret_cast<const bf16x8*>(vb0 + s * 512);
    }
  }

  for (int kt = 0; kt < ntiles; ++kt) {
    // S^T = K x Q (kv tile of 32, d = 8 x 16)
    f32x16 sa = {};
#pragma unroll
    for (int s = 0; s < 8; ++s)
      sa = __builtin_amdgcn_mfma_f32_32x32x16_bf16(kfr[s], qf[s], sa, 0, 0, 0);

    // prefetch next tile's K and V fragments (kfr dead after MFMAs above;
    // vfn is a separate buffer from the vfr consumed below)
    const bool haveNext = (kt + 1 < ntiles);
    if (haveNext) {
      const u16* kbn = kf_ + ((size_t)(bh * 64 + kt + 1) * 8) * 512 + l * 8;
      const u16* vbn = vf_ + ((size_t)(bh * 128 + (kt + 1) * 2) * 4) * 512 + l * 8;
#pragma unroll
      for (int s = 0; s < 8; ++s) {
        kfn[s] = *reinterpret_cast<const bf16x8*>(kbn + s * 512);
        vfn[s] = *reinterpret_cast<const bf16x8*>(vbn + s * 512);
      }
    }

    // scale + (diagonal-only) causal mask + lane-local max
    float p[16];
    float lmax = -INFINITY;
    const bool diag = (kt == qb);
#pragma unroll
    for (int r = 0; r < 16; ++r) {
      float sv = sa[r] * scaleL;
      if (diag) {
        int kv = kt * 32 + (r & 3) + 8 * (r >> 2) + 4 * h;
        if (kv > qrow) sv = -INFINITY;
      }
      p[r] = sv;
      lmax = fmaxf(lmax, sv);
    }
    float rmax = fmaxf(lmax, __shfl_xor(lmax, 32));

    // defer-max rescale
    if (__any(rmax > mrow + 11.5f)) {
      float mnew = fmaxf(mrow, rmax);
      float corr = exp2f(mrow - mnew);
      mrow = mnew;
      lrow *= corr;
#pragma unroll
      for (int r = 0; r < 16; ++r) {
        float cr = __shfl(corr, (r & 3) + 8 * (r >> 2) + 4 * h);
        acc0[r] *= cr; acc1[r] *= cr; acc2[r] *= cr; acc3[r] *= cr;
      }
    }

    // P = 2^(s-m), row sum
    float ls = 0.f;
#pragma unroll
    for (int r = 0; r < 16; ++r) {
      p[r] = exp2f(p[r] - mrow);
      ls += p[r];
    }
    lrow += ls + __shfl_xor(ls, 32);

    // pack P to bf16 pairs, exchange halves, assemble PV A-frags
    u32 w[8];
#pragma unroll
    for (int c = 0; c < 8; ++c)
      asm("v_cvt_pk_bf16_f32 %0, %1, %2" : "=v"(w[c]) : "v"(p[2 * c]), "v"(p[2 * c + 1]));
    u32 x[8];
#pragma unroll
    for (int c = 0; c < 8; ++c) x[c] = (u32)__shfl_xor((int)w[c], 32);
    uint4 A0, A1;
    A0.x = h ? x[2] : w[0]; A0.y = h ? x[3] : w[1];
    A0.z = h ? w[2] : x[0]; A0.w = h ? w[3] : x[1];
    A1.x = h ? x[6] : w[4]; A1.y = h ? x[7] : w[5];
    A1.z = h ? w[6] : x[4]; A1.w = h ? w[7] : x[5];
    bf16x8 pa0 = __builtin_bit_cast(bf16x8, A0);
    bf16x8 pa1 = __builtin_bit_cast(bf16x8, A1);

    // PV: O += P x V (4 d-blocks x 2 kv-halves) — all register-resident
    acc0 = __builtin_amdgcn_mfma_f32_32x32x16_bf16(pa0, vfr[0], acc0, 0, 0, 0);
    acc0 = __builtin_amdgcn_mfma_f32_32x32x16_bf16(pa1, vfr[4], acc0, 0, 0, 0);
    acc1 = __builtin_amdgcn_mfma_f32_32x32x16_bf16(pa0, vfr[1], acc1, 0, 0, 0);
    acc1 = __builtin_amdgcn_mfma_f32_32x32x16_bf16(pa1, vfr[5], acc1, 0, 0, 0);
    acc2 = __builtin_amdgcn_mfma_f32_32x32x16_bf16(pa0, vfr[2], acc2, 0, 0, 0);
    acc2 = __builtin_amdgcn_mfma_f32_32x32x16_bf16(pa1, vfr[6], acc2, 0, 0, 0);
    acc3 = __builtin_amdgcn_mfma_f32_32x32x16_bf16(pa0, vfr[3], acc3, 0, 0, 0);
    acc3 = __builtin_amdgcn_mfma_f32_32x32x16_bf16(pa1, vfr[7], acc3, 0, 0, 0);

    // rotate prefetched K/V fragments into place
    if (haveNext) {
#pragma unroll
      for (int s = 0; s < 8; ++s) { kfr[s] = kfn[s]; vfr[s] = vfn[s]; }
    }
  }

  // epilogue: divide by row-sum (cross-lane fetch), store bf16
  const int b = bh >> 4, hh = bh & 15;
#pragma unroll
  for (int r = 0; r < 16; ++r) {
    int qr = (r & 3) + 8 * (r >> 2) + 4 * h;
    float lr = __shfl(lrow, qr);
    float rl = 1.0f / lr;
    int tt = qb * 32 + qr;
    size_t rowoff = ((size_t)(b * T + tt)) * DM + hh * HD + ln;
    outg[rowoff + 0]  = f2b(acc0[r] * rl);
    outg[rowoff + 32] = f2b(acc1[r] * rl);
    outg[rowoff + 64] = f2b(acc2[r] * rl);
    outg[rowoff + 96] = f2b(acc3[r] * rl);
  }
}

// ---------------- launch ----------------

extern "C" void kernel_launch(void* const* d_in, const int* in_sizes, int n_in,
                              void* d_out, int out_size, void* d_ws, size_t ws_size,
                              hipStream_t stream) {
  const float* x      = (const float*)d_in[0];
  const float* w_qkv  = (const float*)d_in[1];
  const float* w_proj = (const float*)d_in[2];
  const float* w_ff1  = (const float*)d_in[3];
  const float* b_ff1  = (const float*)d_in[4];
  const float* w_ff2  = (const float*)d_in[5];
  const float* b_ff2  = (const float*)d_in[6];
  float* out = (float*)d_out;

  u16* ws = (u16*)d_ws;
  size_t o = 0;
  u16* x_bf      = ws + o; o += (size_t)M * DM;
  u16* wqkv_t    = ws + o; o += (size_t)NQKV * DM;
  u16* wproj_t   = ws + o; o += (size_t)DM * DM;
  u16* wff1_t    = ws + o; o += (size_t)FF * DM;
  u16* wff2_t    = ws + o; o += (size_t)DM * FF;
  u16* attn_proj = ws + o; o += (size_t)M * DM;
  u16* qbuf      = ws + o;                    // qfrag, kfrag, vfrag, attn_out
  u16* kbuf      = qbuf + (size_t)M * DM;
  u16* vbuf      = kbuf + (size_t)M * DM;
  u16* attn_out  = vbuf + (size_t)M * DM;
  u16* hbuf      = qbuf;                      // aliases = M*FF elems

  // FF2 split-K partials alias dead-by-then regions
  float* p0 = (float*)ws;
  float* p1 = (float*)wff1_t;

  // conversions
  cvt_f32_to_bf16<<<(M * DM / 4 + 255) / 256, 256, 0, stream>>>(x, x_bf, M * DM / 4);
  transpose_cvt<<<dim3(NQKV / 32, DM / 32), 256, 0, stream>>>(w_qkv, wqkv_t, DM, NQKV);
  transpose_cvt<<<dim3(DM / 32, DM / 32), 256, 0, stream>>>(w_proj, wproj_t, DM, DM);
  transpose_cvt<<<dim3(FF / 32, DM / 32), 256, 0, stream>>>(w_ff1, wff1_t, DM, FF);
  transpose_cvt<<<dim3(DM / 32, FF / 32), 256, 0, stream>>>(w_ff2, wff2_t, FF, DM);

  // q,k projection -> fragment layout: 4096x4096, 256x256 -> grid 256
  gemm8<0><<<256, 512, 0, stream>>>(x_bf, wqkv_t, 4096, DM, DM, 16, 256,
                                    qbuf, nullptr, nullptr, nullptr);

  // V^T -> fragment layout: 2048x4096, 256x128 -> grid 256
  gemm_bf16<4><<<256, 512, 0, stream>>>(
      wqkv_t + (size_t)4096 * DM, x_bf, M, DM, 32, vbuf);

  // causal flash attention (fragment, no LDS): grid (16, 32), 256 threads
  attn_frag<<<dim3(T / 128, BB * NH), 256, 0, stream>>>(qbuf, kbuf, vbuf, attn_out);

  // output projection: 4096x2048, 256x128 -> grid 256
  gemm_bf16<1><<<256, 512, 0, stream>>>(
      attn_out, wproj_t, DM, DM, 16, attn_proj);

  // FF1 + GELU: 4096x8192, 256x256 -> grid 512
  gemm8<2><<<512, 512, 0, stream>>>(x_bf, wff1_t, FF, DM, DM, 32, 512,
                                    hbuf, nullptr, nullptr, b_ff1);

  // FF2 split-K=2: grid 256, Klen=4096, Kstride=8192
  gemm8<5><<<256, 512, 0, stream>>>(hbuf, wff2_t, DM, FF, 4096, 8, 128,
                                    nullptr, p0, p1, nullptr);

  // join partials + bias + residuals -> f32 out
  ff2_reduce<<<M * DM / 4 / 256, 256, 0, stream>>>(p0, p1, b_ff2, x, attn_proj, out);
}

// Round 20
// 593.264 us; speedup vs baseline: 1.0509x; 1.0509x over previous
//
#include <hip/hip_runtime.h>
#include <hip/hip_bf16.h>
#include <cmath>

typedef __bf16 bf16x8 __attribute__((ext_vector_type(8)));
typedef float f32x4 __attribute__((ext_vector_type(4)));
typedef float f32x16 __attribute__((ext_vector_type(16)));
typedef unsigned short u16;
typedef unsigned int u32;

#define DEV __device__ __forceinline__

static constexpr int BB = 2;
static constexpr int T = 2048;
static constexpr int DM = 2048;
static constexpr int NH = 16;
static constexpr int HD = 128;
static constexpr int FF = 8192;
static constexpr int M = BB * T;      // 4096
static constexpr int NQKV = 3 * DM;   // 6144

DEV u16 f2b(float f) {
  u32 u = __builtin_bit_cast(u32, f);
  u = (u + 0x7FFFu + ((u >> 16) & 1u)) >> 16;
  return (u16)u;
}
DEV float b2f(u16 h) {
  u32 u = ((u32)h) << 16;
  return __builtin_bit_cast(float, u);
}

// async global->LDS, 16B per lane; LDS dest = wave-uniform base + lane*16
DEV void gload16(const u16* g, const u16* l) {
  __builtin_amdgcn_global_load_lds(
      (const __attribute__((address_space(1))) void*)(uintptr_t)g,
      (__attribute__((address_space(3))) void*)(unsigned)(uintptr_t)l,
      16, 0, 0);
}

// ---------------- conversions ----------------

__global__ void cvt_f32_to_bf16(const float* __restrict__ in, u16* __restrict__ out, int n4) {
  int i = blockIdx.x * blockDim.x + threadIdx.x;
  if (i >= n4) return;
  float4 v = reinterpret_cast<const float4*>(in)[i];
  ushort4 o;
  o.x = f2b(v.x); o.y = f2b(v.y); o.z = f2b(v.z); o.w = f2b(v.w);
  reinterpret_cast<ushort4*>(out)[i] = o;
}

// W [K][N] f32 -> Wt [N][K] bf16; 32x32 tile, float4 read + ushort4 write
__global__ void transpose_cvt(const float* __restrict__ W, u16* __restrict__ Wt, int K, int N) {
  __shared__ float tile[32][33];
  int nb = blockIdx.x * 32, kb = blockIdx.y * 32;
  int r = threadIdx.x >> 3;         // 0..31
  int c4 = (threadIdx.x & 7) * 4;   // 0..28
  float4 v = *reinterpret_cast<const float4*>(&W[(size_t)(kb + r) * N + nb + c4]);
  tile[r][c4] = v.x; tile[r][c4 + 1] = v.y; tile[r][c4 + 2] = v.z; tile[r][c4 + 3] = v.w;
  __syncthreads();
  ushort4 o;
  o.x = f2b(tile[c4][r]);     o.y = f2b(tile[c4 + 1][r]);
  o.z = f2b(tile[c4 + 2][r]); o.w = f2b(tile[c4 + 3][r]);
  *reinterpret_cast<ushort4*>(&Wt[(size_t)(nb + r) * K + kb + c4]) = o;
}

// FF2 reduce: out = p0 + p1 + bias + x + attn_proj (split-K join + residuals)
__global__ void ff2_reduce(const float* __restrict__ p0, const float* __restrict__ p1,
                           const float* __restrict__ bias, const float* __restrict__ x,
                           const u16* __restrict__ ap, float* __restrict__ out) {
  int i = blockIdx.x * blockDim.x + threadIdx.x;  // float4 index, exact grid
  float4 a = reinterpret_cast<const float4*>(p0)[i];
  float4 b = reinterpret_cast<const float4*>(p1)[i];
  float4 xx = reinterpret_cast<const float4*>(x)[i];
  float4 bi = reinterpret_cast<const float4*>(bias)[i & (DM / 4 - 1)];
  ushort4 a4 = reinterpret_cast<const ushort4*>(ap)[i];
  float4 o;
  o.x = a.x + b.x + bi.x + xx.x + b2f(a4.x);
  o.y = a.y + b.y + bi.y + xx.y + b2f(a4.y);
  o.z = a.z + b.z + bi.z + xx.z + b2f(a4.z);
  o.w = a.w + b.w + bi.w + xx.w + b2f(a4.w);
  reinterpret_cast<float4*>(out)[i] = o;
}

// ---------------- 8-phase GEMM (256x256, BK=64), balanced reads ----------------
// (frozen schedule — round 13) 8 waves 2M x 4N, wave tile 128x64. 4 phases
// per K-tile, reads spread 4/8/0/12, counted vmcnt(8) publishes tile kt+1 one
// phase early; chunk-XOR swizzle; XCD-bijective block swizzle; setprio.
// EPI 0: q/k fragment scatter; EPI 2: bias+GELU; EPI 5: f32 split-K partial.
template <int EPI>
__global__ __launch_bounds__(512, 2) void gemm8(
    const u16* __restrict__ A, const u16* __restrict__ Bt, int Ndim,
    int Kstride, int Klen, int gx, int tpp,
    u16* __restrict__ out_bf, float* __restrict__ p0, float* __restrict__ p1,
    const float* __restrict__ bias) {
  __shared__ __align__(16) u16 lds[2 * 32768];  // 128 KB
  const int t = threadIdx.x;
  const int nwg = gridDim.x, cpx = nwg >> 3;
  const int wg = (blockIdx.x & 7) * cpx + (blockIdx.x >> 3);
  const int part = wg / tpp, tid = wg % tpp;
  const int m0 = (tid / gx) * 256, n0 = (tid % gx) * 256;
  const int wave = t >> 6, lane = t & 63;
  const int wm = wave >> 2, wn = wave & 3;
  const int lr = lane & 15, lk = lane >> 4;

  const int srow = t >> 3;
  const int sc8 = ((t & 7) ^ (srow & 7)) * 8;
  const u16* gA = &A[(size_t)(m0 + srow) * Kstride + (size_t)part * Klen + sc8];
  const u16* gB = &Bt[(size_t)(n0 + srow) * Kstride + (size_t)part * Klen + sc8];
  const int wls = wave * 512;

  u16* buf0 = lds;
  u16* buf1 = lds + 32768;

#define STAGE_A(buf, h, kt)                                                      \
  {                                                                              \
    gload16(gA + (size_t)((h) * 128) * Kstride + (kt) * 64,                      \
            (buf) + (h) * 8192 + wls);                                           \
    gload16(gA + (size_t)((h) * 128 + 64) * Kstride + (kt) * 64,                 \
            (buf) + (h) * 8192 + 4096 + wls);                                    \
  }
#define STAGE_B(buf, h, kt)                                                      \
  {                                                                              \
    gload16(gB + (size_t)((h) * 128) * Kstride + (kt) * 64,                      \
            (buf) + 16384 + (h) * 8192 + wls);                                   \
    gload16(gB + (size_t)((h) * 128 + 64) * Kstride + (kt) * 64,                 \
            (buf) + 16384 + (h) * 8192 + 4096 + wls);                            \
  }
#define BARR                            \
  __builtin_amdgcn_sched_barrier(0);    \
  __builtin_amdgcn_s_barrier();         \
  __builtin_amdgcn_sched_barrier(0);

  const int NT = Klen >> 6;

  // prologue: all of tile 0 (8 loads), all of tile 1 (8 loads); wait tile 0
  STAGE_B(buf0, 0, 0); STAGE_B(buf0, 1, 0);
  STAGE_A(buf0, 0, 0); STAGE_A(buf0, 1, 0);
  STAGE_B(buf1, 0, 1); STAGE_B(buf1, 1, 1);
  STAGE_A(buf1, 0, 1); STAGE_A(buf1, 1, 1);
  __builtin_amdgcn_sched_barrier(0);
  asm volatile("s_waitcnt vmcnt(8)" ::: "memory");
  __builtin_amdgcn_s_barrier();
  __builtin_amdgcn_sched_barrier(0);

  f32x4 acc[8][4] = {};
  const int aBase = (wm * 128 + lr) * 64;
  const int bBase = 16384 + (wn * 64 + lr) * 64;
  const int c0 = (lk ^ (lr & 7)) * 8;
  const int c1 = ((4 + lk) ^ (lr & 7)) * 8;

  u16* cur = buf0;
  u16* alt = buf1;
  bf16x8 a03[4][2], a47[4][2], b01[2][2], b23[2][2];

  // pre-loop: A03 + B01 of K-tile 0
#pragma unroll
  for (int i = 0; i < 4; ++i) {
    a03[i][0] = *(const bf16x8*)&cur[aBase + i * 1024 + c0];
    a03[i][1] = *(const bf16x8*)&cur[aBase + i * 1024 + c1];
  }
#pragma unroll
  for (int j = 0; j < 2; ++j) {
    b01[j][0] = *(const bf16x8*)&cur[bBase + j * 1024 + c0];
    b01[j][1] = *(const bf16x8*)&cur[bBase + j * 1024 + c1];
  }

  for (int kt = 0; kt < NT; ++kt) {
    // p0: read b23 || MFMA q00(a03,b01)
#pragma unroll
    for (int j = 0; j < 2; ++j) {
      b23[j][0] = *(const bf16x8*)&cur[bBase + (2 + j) * 1024 + c0];
      b23[j][1] = *(const bf16x8*)&cur[bBase + (2 + j) * 1024 + c1];
    }
    __builtin_amdgcn_s_setprio(1);
#pragma unroll
    for (int i = 0; i < 4; ++i)
#pragma unroll
      for (int j = 0; j < 2; ++j)
#pragma unroll
        for (int kk = 0; kk < 2; ++kk)
          acc[i][j] = __builtin_amdgcn_mfma_f32_16x16x32_bf16(a03[i][kk], b01[j][kk], acc[i][j], 0, 0, 0);
    __builtin_amdgcn_s_setprio(0);
    BARR;
    // p1: stage cur.Bh0+Bh1(kt+2); read a47 || MFMA q01(a03,b23)
    if (kt + 2 < NT) { STAGE_B(cur, 0, kt + 2); STAGE_B(cur, 1, kt + 2); }
#pragma unroll
    for (int i = 0; i < 4; ++i) {
      a47[i][0] = *(const bf16x8*)&cur[aBase + (4 + i) * 1024 + c0];
      a47[i][1] = *(const bf16x8*)&cur[aBase + (4 + i) * 1024 + c1];
    }
    __builtin_amdgcn_s_setprio(1);
#pragma unroll
    for (int i = 0; i < 4; ++i)
#pragma unroll
      for (int j = 0; j < 2; ++j)
#pragma unroll
        for (int kk = 0; kk < 2; ++kk)
          acc[i][2 + j] = __builtin_amdgcn_mfma_f32_16x16x32_bf16(a03[i][kk], b23[j][kk], acc[i][2 + j], 0, 0, 0);
    __builtin_amdgcn_s_setprio(0);
    BARR;
    // p2: stage cur.Ah0+Ah1(kt+2); MFMA q10(a47,b01); publish tile kt+1
    if (kt + 2 < NT) { STAGE_A(cur, 0, kt + 2); STAGE_A(cur, 1, kt + 2); }
    __builtin_amdgcn_s_setprio(1);
#pragma unroll
    for (int i = 0; i < 4; ++i)
#pragma unroll
      for (int j = 0; j < 2; ++j)
#pragma unroll
        for (int kk = 0; kk < 2; ++kk)
          acc[4 + i][j] = __builtin_amdgcn_mfma_f32_16x16x32_bf16(a47[i][kk], b01[j][kk], acc[4 + i][j], 0, 0, 0);
    __builtin_amdgcn_s_setprio(0);
    __builtin_amdgcn_sched_barrier(0);
    if (kt + 2 < NT)      asm volatile("s_waitcnt vmcnt(8)" ::: "memory");
    else if (kt + 1 < NT) asm volatile("s_waitcnt vmcnt(0)" ::: "memory");
    __builtin_amdgcn_s_barrier();
    __builtin_amdgcn_sched_barrier(0);
    // p3: read NEXT a03/b01 from alt || MFMA q11(a47,b23)
    if (kt + 1 < NT) {
#pragma unroll
      for (int i = 0; i < 4; ++i) {
        a03[i][0] = *(const bf16x8*)&alt[aBase + i * 1024 + c0];
        a03[i][1] = *(const bf16x8*)&alt[aBase + i * 1024 + c1];
      }
#pragma unroll
      for (int j = 0; j < 2; ++j) {
        b01[j][0] = *(const bf16x8*)&alt[bBase + j * 1024 + c0];
        b01[j][1] = *(const bf16x8*)&alt[bBase + j * 1024 + c1];
      }
    }
    __builtin_amdgcn_s_setprio(1);
#pragma unroll
    for (int i = 0; i < 4; ++i)
#pragma unroll
      for (int j = 0; j < 2; ++j)
#pragma unroll
        for (int kk = 0; kk < 2; ++kk)
          acc[4 + i][2 + j] = __builtin_amdgcn_mfma_f32_16x16x32_bf16(a47[i][kk], b23[j][kk], acc[4 + i][2 + j], 0, 0, 0);
    __builtin_amdgcn_s_setprio(0);
    BARR;
    u16* tmp = cur; cur = alt; alt = tmp;
  }
#undef STAGE_A
#undef STAGE_B
#undef BARR

  float* pout = (part == 0) ? p0 : p1;
#pragma unroll
  for (int i = 0; i < 8; ++i) {
#pragma unroll
    for (int j = 0; j < 4; ++j) {
#pragma unroll
      for (int r = 0; r < 4; ++r) {
        int gr = m0 + wm * 128 + i * 16 + (lane >> 4) * 4 + r;
        int gc = n0 + wn * 64 + j * 16 + (lane & 15);
        float v = acc[i][j][r];
        if constexpr (EPI == 0) {
          // q/k scatter in fragment layout:
          // frag[bh][tb=tt>>5][s=d>>4][lane=(tt&31)+32*((d>>3)&1)][j=d&7]
          int part_ = gc >> 11, cc = gc & 2047;
          int head = cc >> 7, d = cc & 127;
          int b = gr >> 11, tt = gr & 2047;
          int bh = b * NH + head;
          size_t addr = (((size_t)(bh * 64 + (tt >> 5)) * 8 + (d >> 4)) * 512)
                        + ((tt & 31) + ((d >> 3) & 1) * 32) * 8 + (d & 7);
          out_bf[(size_t)part_ * M * DM + addr] = f2b(v);
        } else if constexpr (EPI == 2) {  // bias + tanh-GELU
          v += bias[gc];
          float u = v * (v * v * 0.044715f + 1.0f) * 0.7978845608028654f;
          float e = exp2f(u * 2.885390081777927f);
          float th = 1.0f - 2.0f / (e + 1.0f);
          v = 0.5f * v * (1.0f + th);
          out_bf[(size_t)gr * Ndim + gc] = f2b(v);
        } else {  // EPI 5: f32 partial
          pout[(size_t)gr * Ndim + gc] = v;
        }
      }
    }
  }
}

// ---------------- GEMM (256x128, 8 waves 64x64) ----------------
// (verified) 3-buffer pipeline, counted vmcnt(3), raw s_barrier, chunk
// swizzle, XCD-bijective block swizzle.
// EPI 1: plain bf16; EPI 4: V-FRAGMENT scatter.
template <int EPI>
__global__ __launch_bounds__(512, 4) void gemm_bf16(
    const u16* __restrict__ A, const u16* __restrict__ Bt, int Ndim, int K, int gx,
    u16* __restrict__ out_bf) {
  __shared__ __align__(16) u16 lds[3 * (256 + 128) * 32];  // 72 KB
  const int t = threadIdx.x;
  const int nwg = gridDim.x, cpx = nwg >> 3;
  const int wg = (blockIdx.x & 7) * cpx + (blockIdx.x >> 3);
  const int m0 = (wg / gx) * 256, n0 = (wg % gx) * 128;
  const int wave = t >> 6, lane = t & 63;
  const int wm = wave >> 1, wn = wave & 1;
  const int lr = lane & 15, lk = lane >> 4;

  u16* cA = lds;                   u16* cB = lds + 8192;
  u16* nA = lds + 12288;           u16* nB = lds + 12288 + 8192;
  u16* sA = lds + 2 * 12288;       u16* sB = lds + 2 * 12288 + 8192;

  const int sk = ((lane & 3) ^ ((lane >> 3) & 3)) * 8;
  const u16* gA0 = &A[(size_t)(m0 + wave * 16 + (lane >> 2)) * K + sk];
  const u16* gA1 = gA0 + (size_t)128 * K;
  const u16* gB0 = &Bt[(size_t)(n0 + wave * 16 + (lane >> 2)) * K + sk];

  const int wbase = wave * 512;

  auto stage = [&](u16* dA, u16* dB) {
    gload16(gA0, dA + wbase);
    gload16(gA1, dA + 4096 + wbase);
    gload16(gB0, dB + wbase);
    gA0 += 32; gA1 += 32; gB0 += 32;
  };

  const int NT = K >> 5;

  stage(cA, cB);
  stage(nA, nB);
  __builtin_amdgcn_sched_barrier(0);
  asm volatile("s_waitcnt vmcnt(3)" ::: "memory");
  __builtin_amdgcn_s_barrier();
  __builtin_amdgcn_sched_barrier(0);

  f32x4 acc[4][4] = {};
  const int rcol = (lk ^ ((lr >> 1) & 3)) * 8;

  for (int kt = 0; kt < NT; ++kt) {
    if (kt + 2 < NT) stage(sA, sB);
    bf16x8 af[4], bfr[4];
#pragma unroll
    for (int i = 0; i < 4; ++i) {
      af[i]  = *reinterpret_cast<const bf16x8*>(&cA[(wm * 64 + i * 16 + lr) * 32 + rcol]);
      bfr[i] = *reinterpret_cast<const bf16x8*>(&cB[(wn * 64 + i * 16 + lr) * 32 + rcol]);
    }
#pragma unroll
    for (int i = 0; i < 4; ++i)
#pragma unroll
      for (int j = 0; j < 4; ++j)
        acc[i][j] = __builtin_amdgcn_mfma_f32_16x16x32_bf16(af[i], bfr[j], acc[i][j], 0, 0, 0);
    if (kt + 1 < NT) {
      __builtin_amdgcn_sched_barrier(0);
      if (kt + 2 < NT) asm volatile("s_waitcnt vmcnt(3)" ::: "memory");
      else             asm volatile("s_waitcnt vmcnt(0)" ::: "memory");
      __builtin_amdgcn_s_barrier();
      __builtin_amdgcn_sched_barrier(0);
      u16* tA = cA; u16* tB = cB;
      cA = nA; cB = nB; nA = sA; nB = sB; sA = tA; sB = tB;
    }
  }

#pragma unroll
  for (int i = 0; i < 4; ++i) {
#pragma unroll
    for (int j = 0; j < 4; ++j) {
#pragma unroll
      for (int r = 0; r < 4; ++r) {
        int gr = m0 + wm * 64 + i * 16 + (lane >> 4) * 4 + r;
        int gc = n0 + wn * 64 + j * 16 + (lane & 15);
        float v = acc[i][j][r];
        if constexpr (EPI == 1) {
          out_bf[(size_t)gr * Ndim + gc] = f2b(v);
        } else {
          // EPI 4: V fragment layout. This GEMM computes V^T: gr = feature
          // (hh*128+d), gc = token (b*2048+tt).
          // vfrag[bh][kv16=tt>>4][dblk=d>>5][lane=(d&31)+32*((tt>>3)&1)][j=tt&7]
          int hh = gr >> 7, d = gr & 127;
          int b = gc >> 11, tt = gc & 2047;
          int bh = b * NH + hh;
          size_t addr = (((size_t)(bh * 128 + (tt >> 4)) * 4 + (d >> 5)) * 512)
                        + ((d & 31) + ((tt >> 3) & 1) * 32) * 8 + (tt & 7);
          out_bf[addr] = f2b(v);
        }
      }
    }
  }
}

// ---------------- attention (fragment-layout, 32x32 MFMA, no LDS) ----------
// (verified round 18 — best measured) grid (T/128, B*NH), 4 waves x 32 q-rows.
// Register K-prefetch: tile kt+1's K loads issue right after tile kt's
// S-MFMAs consume the current fragments; softmax+pack+PV covers the latency.
// launch_bounds(256,2) caps VGPR at 256 (2 waves/SIMD). V loads stay in the
// PV section (V-prefetch spilled — round 19 regression, reverted).
__global__ __launch_bounds__(256, 2) void attn_frag(
    const u16* __restrict__ qf_, const u16* __restrict__ kf_,
    const u16* __restrict__ vf_, u16* __restrict__ outg) {
  const int l = threadIdx.x & 63;
  const int wq = threadIdx.x >> 6;
  const int bh = blockIdx.y;
  const int qi = gridDim.x - 1 - blockIdx.x;  // longest-first
  const int qb = qi * 4 + wq;                 // 32-row band index, 0..63
  const int h = l >> 5, ln = l & 31;
  const int qrow = qb * 32 + ln;              // this lane's q-row

  // Q fragments (8 d-slices)
  const u16* qbase = qf_ + ((size_t)(bh * 64 + qb) * 8) * 512 + l * 8;
  bf16x8 qf[8];
#pragma unroll
  for (int s = 0; s < 8; ++s)
    qf[s] = *reinterpret_cast<const bf16x8*>(qbase + s * 512);

  f32x16 acc0 = {}, acc1 = {}, acc2 = {}, acc3 = {};
  float mrow = -INFINITY, lrow = 0.f;
  const float scaleL = 0.08838834764831845f * 1.4426950408889634f;
  const int ntiles = qb + 1;

  // prologue: K fragments of tile 0
  bf16x8 kfr[8], kfn[8];
  {
    const u16* kb0 = kf_ + ((size_t)(bh * 64 + 0) * 8) * 512 + l * 8;
#pragma unroll
    for (int s = 0; s < 8; ++s)
      kfr[s] = *reinterpret_cast<const bf16x8*>(kb0 + s * 512);
  }

  for (int kt = 0; kt < ntiles; ++kt) {
    // S^T = K x Q (kv tile of 32, d = 8 x 16)
    f32x16 sa = {};
#pragma unroll
    for (int s = 0; s < 8; ++s)
      sa = __builtin_amdgcn_mfma_f32_32x32x16_bf16(kfr[s], qf[s], sa, 0, 0, 0);

    // prefetch next tile's K fragments (kfr dead after the MFMAs above)
    const bool haveNext = (kt + 1 < ntiles);
    if (haveNext) {
      const u16* kbn = kf_ + ((size_t)(bh * 64 + kt + 1) * 8) * 512 + l * 8;
#pragma unroll
      for (int s = 0; s < 8; ++s)
        kfn[s] = *reinterpret_cast<const bf16x8*>(kbn + s * 512);
    }

    // scale + (diagonal-only) causal mask + lane-local max
    float p[16];
    float lmax = -INFINITY;
    const bool diag = (kt == qb);
#pragma unroll
    for (int r = 0; r < 16; ++r) {
      float sv = sa[r] * scaleL;
      if (diag) {
        int kv = kt * 32 + (r & 3) + 8 * (r >> 2) + 4 * h;
        if (kv > qrow) sv = -INFINITY;
      }
      p[r] = sv;
      lmax = fmaxf(lmax, sv);
    }
    float rmax = fmaxf(lmax, __shfl_xor(lmax, 32));

    // defer-max rescale
    if (__any(rmax > mrow + 11.5f)) {
      float mnew = fmaxf(mrow, rmax);
      float corr = exp2f(mrow - mnew);
      mrow = mnew;
      lrow *= corr;
#pragma unroll
      for (int r = 0; r < 16; ++r) {
        float cr = __shfl(corr, (r & 3) + 8 * (r >> 2) + 4 * h);
        acc0[r] *= cr; acc1[r] *= cr; acc2[r] *= cr; acc3[r] *= cr;
      }
    }

    // P = 2^(s-m), row sum
    float ls = 0.f;
#pragma unroll
    for (int r = 0; r < 16; ++r) {
      p[r] = exp2f(p[r] - mrow);
      ls += p[r];
    }
    lrow += ls + __shfl_xor(ls, 32);

    // pack P to bf16 pairs, exchange halves, assemble PV A-frags
    u32 w[8];
#pragma unroll
    for (int c = 0; c < 8; ++c)
      asm("v_cvt_pk_bf16_f32 %0, %1, %2" : "=v"(w[c]) : "v"(p[2 * c]), "v"(p[2 * c + 1]));
    u32 x[8];
#pragma unroll
    for (int c = 0; c < 8; ++c) x[c] = (u32)__shfl_xor((int)w[c], 32);
    uint4 A0, A1;
    A0.x = h ? x[2] : w[0]; A0.y = h ? x[3] : w[1];
    A0.z = h ? w[2] : x[0]; A0.w = h ? w[3] : x[1];
    A1.x = h ? x[6] : w[4]; A1.y = h ? x[7] : w[5];
    A1.z = h ? w[6] : x[4]; A1.w = h ? w[7] : x[5];
    bf16x8 pa0 = __builtin_bit_cast(bf16x8, A0);
    bf16x8 pa1 = __builtin_bit_cast(bf16x8, A1);

    // PV: O += P x V (4 d-blocks x 2 kv-halves)
    const u16* vbase = vf_ + ((size_t)(bh * 128 + kt * 2) * 4) * 512 + l * 8;
    bf16x8 v0, v1;
    v0 = *reinterpret_cast<const bf16x8*>(vbase + 0 * 512);
    v1 = *reinterpret_cast<const bf16x8*>(vbase + 4 * 512);
    acc0 = __builtin_amdgcn_mfma_f32_32x32x16_bf16(pa0, v0, acc0, 0, 0, 0);
    acc0 = __builtin_amdgcn_mfma_f32_32x32x16_bf16(pa1, v1, acc0, 0, 0, 0);
    v0 = *reinterpret_cast<const bf16x8*>(vbase + 1 * 512);
    v1 = *reinterpret_cast<const bf16x8*>(vbase + 5 * 512);
    acc1 = __builtin_amdgcn_mfma_f32_32x32x16_bf16(pa0, v0, acc1, 0, 0, 0);
    acc1 = __builtin_amdgcn_mfma_f32_32x32x16_bf16(pa1, v1, acc1, 0, 0, 0);
    v0 = *reinterpret_cast<const bf16x8*>(vbase + 2 * 512);
    v1 = *reinterpret_cast<const bf16x8*>(vbase + 6 * 512);
    acc2 = __builtin_amdgcn_mfma_f32_32x32x16_bf16(pa0, v0, acc2, 0, 0, 0);
    acc2 = __builtin_amdgcn_mfma_f32_32x32x16_bf16(pa1, v1, acc2, 0, 0, 0);
    v0 = *reinterpret_cast<const bf16x8*>(vbase + 3 * 512);
    v1 = *reinterpret_cast<const bf16x8*>(vbase + 7 * 512);
    acc3 = __builtin_amdgcn_mfma_f32_32x32x16_bf16(pa0, v0, acc3, 0, 0, 0);
    acc3 = __builtin_amdgcn_mfma_f32_32x32x16_bf16(pa1, v1, acc3, 0, 0, 0);

    // rotate prefetched K fragments into place
    if (haveNext) {
#pragma unroll
      for (int s = 0; s < 8; ++s) kfr[s] = kfn[s];
    }
  }

  // epilogue: divide by row-sum (cross-lane fetch), store bf16
  const int b = bh >> 4, hh = bh & 15;
#pragma unroll
  for (int r = 0; r < 16; ++r) {
    int qr = (r & 3) + 8 * (r >> 2) + 4 * h;
    float lr = __shfl(lrow, qr);
    float rl = 1.0f / lr;
    int tt = qb * 32 + qr;
    size_t rowoff = ((size_t)(b * T + tt)) * DM + hh * HD + ln;
    outg[rowoff + 0]  = f2b(acc0[r] * rl);
    outg[rowoff + 32] = f2b(acc1[r] * rl);
    outg[rowoff + 64] = f2b(acc2[r] * rl);
    outg[rowoff + 96] = f2b(acc3[r] * rl);
  }
}

// ---------------- launch ----------------

extern "C" void kernel_launch(void* const* d_in, const int* in_sizes, int n_in,
                              void* d_out, int out_size, void* d_ws, size_t ws_size,
                              hipStream_t stream) {
  const float* x      = (const float*)d_in[0];
  const float* w_qkv  = (const float*)d_in[1];
  const float* w_proj = (const float*)d_in[2];
  const float* w_ff1  = (const float*)d_in[3];
  const float* b_ff1  = (const float*)d_in[4];
  const float* w_ff2  = (const float*)d_in[5];
  const float* b_ff2  = (const float*)d_in[6];
  float* out = (float*)d_out;

  u16* ws = (u16*)d_ws;
  size_t o = 0;
  u16* x_bf      = ws + o; o += (size_t)M * DM;
  u16* wqkv_t    = ws + o; o += (size_t)NQKV * DM;
  u16* wproj_t   = ws + o; o += (size_t)DM * DM;
  u16* wff1_t    = ws + o; o += (size_t)FF * DM;
  u16* wff2_t    = ws + o; o += (size_t)DM * FF;
  u16* attn_proj = ws + o; o += (size_t)M * DM;
  u16* qbuf      = ws + o;                    // qfrag, kfrag, vfrag, attn_out
  u16* kbuf      = qbuf + (size_t)M * DM;
  u16* vbuf      = kbuf + (size_t)M * DM;
  u16* attn_out  = vbuf + (size_t)M * DM;
  u16* hbuf      = qbuf;                      // aliases = M*FF elems

  // FF2 split-K partials alias dead-by-then regions
  float* p0 = (float*)ws;
  float* p1 = (float*)wff1_t;

  // conversions
  cvt_f32_to_bf16<<<(M * DM / 4 + 255) / 256, 256, 0, stream>>>(x, x_bf, M * DM / 4);
  transpose_cvt<<<dim3(NQKV / 32, DM / 32), 256, 0, stream>>>(w_qkv, wqkv_t, DM, NQKV);
  transpose_cvt<<<dim3(DM / 32, DM / 32), 256, 0, stream>>>(w_proj, wproj_t, DM, DM);
  transpose_cvt<<<dim3(FF / 32, DM / 32), 256, 0, stream>>>(w_ff1, wff1_t, DM, FF);
  transpose_cvt<<<dim3(DM / 32, FF / 32), 256, 0, stream>>>(w_ff2, wff2_t, FF, DM);

  // q,k projection -> fragment layout: 4096x4096, 256x256 -> grid 256
  gemm8<0><<<256, 512, 0, stream>>>(x_bf, wqkv_t, 4096, DM, DM, 16, 256,
                                    qbuf, nullptr, nullptr, nullptr);

  // V^T -> fragment layout: 2048x4096, 256x128 -> grid 256
  gemm_bf16<4><<<256, 512, 0, stream>>>(
      wqkv_t + (size_t)4096 * DM, x_bf, M, DM, 32, vbuf);

  // causal flash attention (fragment, no LDS): grid (16, 32), 256 threads
  attn_frag<<<dim3(T / 128, BB * NH), 256, 0, stream>>>(qbuf, kbuf, vbuf, attn_out);

  // output projection: 4096x2048, 256x128 -> grid 256
  gemm_bf16<1><<<256, 512, 0, stream>>>(
      attn_out, wproj_t, DM, DM, 16, attn_proj);

  // FF1 + GELU: 4096x8192, 256x256 -> grid 512
  gemm8<2><<<512, 512, 0, stream>>>(x_bf, wff1_t, FF, DM, DM, 32, 512,
                                    hbuf, nullptr, nullptr, b_ff1);

  // FF2 split-K=2: grid 256, Klen=4096, Kstride=8192
  gemm8<5><<<256, 512, 0, stream>>>(hbuf, wff2_t, DM, FF, 4096, 8, 128,
                                    nullptr, p0, p1, nullptr);

  // join partials + bias + residuals -> f32 out
  ff2_reduce<<<M * DM / 4 / 256, 256, 0, stream>>>(p0, p1, b_ff2, x, attn_proj, out);
}